// Round 1
// 90.448 us; speedup vs baseline: 1.0176x; 1.0176x over previous
//
#include <hip/hip_runtime.h>
#include <stdint.h>

typedef unsigned short u16;
typedef unsigned int u32;
typedef unsigned long long u64;

typedef __bf16 bf16x8 __attribute__((ext_vector_type(8)));
typedef float f32x4 __attribute__((ext_vector_type(4)));
typedef u16 u16x8 __attribute__((ext_vector_type(8)));

#define NQ 512
#define NC 16
#define NH 128
#define NB 2048
#define QE_KEYS (513*128)          // 65664 u16 keys
#define WT_OFF  QE_KEYS            // bf16 W copy
#define GW_ELEMS (128*128)
#define A_OFF (WT_OFF + GW_ELEMS)  // a_norm bf16, padded 16x32 (K 16->32 zeros)
#define LSEG 1088                  // per-item list segment (16*64=1024 + pad), u16
#define ESEG 2304                  // per-item sE segment (16*136=2176 + pad), u16
#define ESTRIDE 136

static __device__ __forceinline__ u16 f2bf_rne(float f){
  u32 u = __float_as_uint(f);
  u += 0x7fffu + ((u>>16)&1u);
  return (u16)(u>>16);
}
static __device__ __forceinline__ u32 pack_rne(float lo, float hi){
  return (u32)f2bf_rne(lo) | ((u32)f2bf_rne(hi)<<16);
}
// monotone key: unsigned compare on keys == float compare on bf16 values
static __device__ __forceinline__ u16 key_of(float f){
  u16 b = f2bf_rne(f);
  return (b & 0x8000u) ? (u16)~b : (u16)(b | 0x8000u);
}
static __device__ __forceinline__ u16 unkey(u16 k){
  return (k & 0x8000u) ? (u16)(k ^ 0x8000u) : (u16)~k;
}

union Frag { u32 u[4]; uint4 u4; bf16x8 f; };
union U8   { u16x8 v; int w[4]; uint4 u4; u16 h[8]; };

// ---- prepass: keys, bf16 W, and precomputed a_norm A-fragment table ----
__global__ void prepass_kernel(const float* __restrict__ qe,
                               const float* __restrict__ gw,
                               const float* __restrict__ adj,
                               u16* __restrict__ ws)
{
  if (blockIdx.x == 0) {            // a_norm = adj * dinv_i * dinv_j, padded 16x32
    __shared__ float sD[16];
    int t = threadIdx.x;
    if (t < 16) {
      float s = 0.f;
      for (int i = 0; i < 16; ++i) s += adj[i*16 + t];
      sD[t] = (s > 0.f) ? (1.0f / sqrtf(s)) : 0.f;
    }
    __syncthreads();
    int i = t >> 4, jp = (t & 15) * 2;   // row i, cols jp, jp+1 of 32
    float lo = (jp   < 16) ? adj[i*16 + jp]   * sD[i] * sD[jp]   : 0.f;
    float hi = (jp+1 < 16) ? adj[i*16 + jp+1] * sD[i] * sD[jp+1] : 0.f;
    ((u32*)(ws + A_OFF))[t] = pack_rne(lo, hi);
    return;
  }
  int idx = (blockIdx.x - 1) * 256 + threadIdx.x;
  if (idx < QE_KEYS/8) {                       // key table
    int i8 = idx * 8;
    uint4 o;
    if (i8 >= 512*NH) {                        // row 512: key of +0.0
      o.x = 0x80008000u; o.y = 0x80008000u; o.z = 0x80008000u; o.w = 0x80008000u;
    } else {
      const float4* p = (const float4*)(qe + i8);
      float4 a = p[0], b = p[1];
      o.x = (u32)key_of(a.x) | ((u32)key_of(a.y)<<16);
      o.y = (u32)key_of(a.z) | ((u32)key_of(a.w)<<16);
      o.z = (u32)key_of(b.x) | ((u32)key_of(b.y)<<16);
      o.w = (u32)key_of(b.z) | ((u32)key_of(b.w)<<16);
    }
    *(uint4*)(ws + i8) = o;
  } else if (idx < QE_KEYS/8 + GW_ELEMS/8) {   // W -> bf16
    int j8 = (idx - QE_KEYS/8) * 8;
    const float4* p = (const float4*)(gw + j8);
    float4 a = p[0], b = p[1];
    uint4 o;
    o.x = pack_rne(a.x, a.y); o.y = pack_rne(a.z, a.w);
    o.z = pack_rne(b.x, b.y); o.w = pack_rne(b.z, b.w);
    *(uint4*)(ws + WT_OFF + j8) = o;
  }
}

static __device__ __forceinline__ void wave_reduce_max(U8& A){
  U8 B;
  #pragma unroll
  for (int j = 0; j < 4; ++j) B.w[j] = __shfl_xor(A.w[j], 16);
  A.v = __builtin_elementwise_max(A.v, B.v);
  #pragma unroll
  for (int j = 0; j < 4; ++j) B.w[j] = __shfl_xor(A.w[j], 32);
  A.v = __builtin_elementwise_max(A.v, B.v);
}

// TEAM OF 2 WAVES per item: block = 256 threads = 2 items.
// grid = NB/2 = 1024 blocks -> 4 blocks/CU = 16 waves/CU (2x the old occupancy),
// and every per-wave serial chain (phase-1 chunks, phase-2 cores, phase-3/4
// o-tiles) halves. Cross-wave data (rank bases, sE) goes through LDS + barriers.
__global__ __launch_bounds__(256, 4)
void core_snapshot_kernel(const int* __restrict__ la,
                          const u16* __restrict__ ws,
                          const float* __restrict__ gb,
                          float* __restrict__ outp)
{
  __shared__ __align__(16) u16 sListAll[2*LSEG];
  __shared__ __align__(16) u16 sEAll[2*ESEG];
  __shared__ int sCnt[2][2][16];    // [item][teamwave][core]

  const int tid  = threadIdx.x;
  const int lane = tid & 63;
  const int wv   = tid >> 6;
  const int it   = wv >> 1;         // item slot within block (0,1)
  const int tw   = wv & 1;          // team-wave index (0,1)
  const int m    = lane & 15;
  const int quad = lane >> 4;
  const int item = blockIdx.x*2 + it;
  u16* sList = sListAll + it*LSEG;
  u16* sE    = sEAll    + it*ESEG;
  const u16* qt = ws;
  const u16* wt = ws + WT_OFF;

  // prefill private list with 512 (pads gather the key-0 row == reference pad
  // semantics). Each wave fills half of the 1024 entries.
  {
    uint4 f = make_uint4(0x02000200u,0x02000200u,0x02000200u,0x02000200u);
    *(uint4*)&sList[tw*512 + lane*8] = f;
  }
  __syncthreads();   // B1: prefill complete before any entry writes

  // ---- phase 1: 4 chunks per wave; wave1 ranks offset by wave0 totals ----
  int av[4];
  #pragma unroll
  for (int ch = 0; ch < 4; ++ch) av[ch] = la[item*NQ + (tw*4 + ch)*64 + lane];
  const u64 lmask = (1ull << lane) - 1ull;
  u32 runbase = 0;     // lane c (<16) holds running count for core c (this wave)
  u32 rankrel[4];
  #pragma unroll
  for (int ch = 0; ch < 4; ++ch) {
    u32 cnt = 0, intra = 0;
    #pragma unroll
    for (int c = 0; c < 16; ++c) {
      u64 mk = __ballot(av[ch] == c);
      if (lane == c)    cnt   = (u32)__popcll(mk);
      if (av[ch] == c)  intra = (u32)__popcll(mk & lmask);
    }
    u32 base = (u32)__shfl((int)runbase, av[ch]);   // pre-chunk base, this wave
    rankrel[ch] = base + intra;
    runbase += cnt;
  }
  if (lane < 16) sCnt[it][tw][lane] = (int)runbase;
  if (tw == 0) {
    // wave0 ranks are final (base 0)
    #pragma unroll
    for (int ch = 0; ch < 4; ++ch) {
      u32 rank = rankrel[ch];
      // transposed: quad q's 16 entries [q*16+k] hold ranks q+4k
      if (rank < 64) sList[av[ch]*64 + (rank&3)*16 + (rank>>2)] = (u16)(ch*64 + lane);
    }
  }
  __syncthreads();   // B2: wave0 entries + both waves' counts visible
  u32 cntv;          // lane c: TOTAL count of core c (both waves)
  if (tw == 1) {
    #pragma unroll
    for (int ch = 0; ch < 4; ++ch) {
      u32 rank = (u32)sCnt[it][0][av[ch]] + rankrel[ch];
      if (rank < 64) sList[av[ch]*64 + (rank&3)*16 + (rank>>2)] = (u16)((4 + ch)*64 + lane);
    }
    cntv = runbase + (u32)((lane < 16) ? sCnt[it][0][lane] : 0);
  } else {
    cntv = runbase + (u32)((lane < 16) ? sCnt[it][1][lane] : 0);
  }
  __syncthreads();   // B3: all list entries visible

  // ---- phase 2: 8 cores per wave; gather from L2, packed-u16 max ----
  // batch granularity 32/16/16 ranks: E[rows/core] ~40 vs 48 before.
  const u16* qb = qt + m*8;   // this lane's 8-dim chunk
  for (int cc = 0; cc < 8; ++cc) {
    int c = tw*8 + cc;
    int cnt = __shfl((int)cntv, c);
    U8 S0, S1;
    S0.u4 = *(const uint4*)&sList[c*64 + quad*16];      // ranks quad+4k, k=0..7
    S1.u4 = *(const uint4*)&sList[c*64 + quad*16 + 8];  // k=8..15
    U8 A; A.v = (u16x8)0;                               // key 0 < all value keys
    {
      U8 T[8];
      #pragma unroll
      for (int k = 0; k < 8; ++k) T[k].u4 = *(const uint4*)(qb + (int)S0.h[k]*NH);
      #pragma unroll
      for (int k = 0; k < 8; ++k) A.v = __builtin_elementwise_max(A.v, T[k].v);
    }
    if (cnt > 32) {   // wave-uniform; ranks 32..47 (pads give key(+0))
      U8 T[4];
      #pragma unroll
      for (int k = 0; k < 4; ++k) T[k].u4 = *(const uint4*)(qb + (int)S1.h[k]*NH);
      #pragma unroll
      for (int k = 0; k < 4; ++k) A.v = __builtin_elementwise_max(A.v, T[k].v);
    }
    if (cnt > 48) {   // ranks 48..63
      U8 T[4];
      #pragma unroll
      for (int k = 0; k < 4; ++k) T[k].u4 = *(const uint4*)(qb + (int)S1.h[4+k]*NH);
      #pragma unroll
      for (int k = 0; k < 4; ++k) A.v = __builtin_elementwise_max(A.v, T[k].v);
    }
    wave_reduce_max(A);
    if (cnt < 64) {   // relu via key(+0) (redundant with pads, kept for robustness)
      U8 Z; Z.v = (u16x8)(u16)0x8000u;
      A.v = __builtin_elementwise_max(A.v, Z.v);
    }
    if (quad == 0) {
      uint4 e;
      e.x = (u32)unkey(A.h[0]) | ((u32)unkey(A.h[1])<<16);
      e.y = (u32)unkey(A.h[2]) | ((u32)unkey(A.h[3])<<16);
      e.z = (u32)unkey(A.h[4]) | ((u32)unkey(A.h[5])<<16);
      e.w = (u32)unkey(A.h[6]) | ((u32)unkey(A.h[7])<<16);
      *(uint4*)&sE[c*ESTRIDE + m*8] = e;
    }
  }
  __syncthreads();   // B4: full sE visible to both waves

  // ---- phases 3+4 fused per o-tile (4 tiles per wave) ----
  bf16x8 af[4];   // E A-fragments
  #pragma unroll
  for (int ks = 0; ks < 4; ++ks)
    af[ks] = *(const bf16x8*)&sE[m*ESTRIDE + ks*32 + quad*8];
  Frag anf;       // a_norm A-fragment (precomputed, padded K zeros)
  anf.u4 = *(const uint4*)(ws + A_OFF + m*32 + quad*8);

  #pragma unroll
  for (int tt = 0; tt < 4; ++tt) {
    int t = tw*4 + tt;
    // H tile: C-layout acc[r] = H[core=quad*4+r][o=t*16+m]
    f32x4 acc = {0.f, 0.f, 0.f, 0.f};
    #pragma unroll
    for (int ks = 0; ks < 4; ++ks) {
      bf16x8 bfr = *(const bf16x8*)(wt + (t*16 + m)*NH + ks*32 + quad*8);
      acc = __builtin_amdgcn_mfma_f32_16x16x32_bf16(af[ks], bfr, acc, 0, 0, 0);
    }
    // B-frag for out-GEMM: lane(m,q) j-th elem = H[core=q*8+j][o=t*16+m], q<2
    float d16[4], d32[4], lo[4], hi[4];
    #pragma unroll
    for (int r = 0; r < 4; ++r) {
      d16[r] = __shfl_down(acc[r], 16);
      d32[r] = __shfl_down(acc[r], 32);
    }
    #pragma unroll
    for (int r = 0; r < 4; ++r) {
      lo[r] = (quad == 0) ? acc[r] : d16[r];
      hi[r] = (quad == 0) ? d16[r] : d32[r];
    }
    Frag hb;
    hb.u[0] = pack_rne(lo[0], lo[1]); hb.u[1] = pack_rne(lo[2], lo[3]);
    hb.u[2] = pack_rne(hi[0], hi[1]); hb.u[3] = pack_rne(hi[2], hi[3]);
    if (quad >= 2) { hb.u[0]=0; hb.u[1]=0; hb.u[2]=0; hb.u[3]=0; }  // K-pad
    float biasv = gb[t*16 + m];
    f32x4 o4 = {biasv, biasv, biasv, biasv};
    o4 = __builtin_amdgcn_mfma_f32_16x16x32_bf16(anf.f, hb.f, o4, 0, 0, 0);
    // C/D: col=lane&15 (o in tile), row=quad*4+reg (core)
    float* op = outp + item*(NC*NH) + t*16 + m;
    #pragma unroll
    for (int r = 0; r < 4; ++r) op[(quad*4 + r)*NH] = o4[r];
  }
}

extern "C" void kernel_launch(void* const* d_in, const int* in_sizes, int n_in,
                              void* d_out, int out_size, void* d_ws, size_t ws_size,
                              hipStream_t stream) {
  const int*   la  = (const int*)d_in[0];    // (2048, 512) int32
  const float* adj = (const float*)d_in[1];  // (16,16) fp32
  const float* qe  = (const float*)d_in[2];  // (513,128) fp32
  const float* gw  = (const float*)d_in[3];  // (128,128) fp32
  const float* gb  = (const float*)d_in[4];  // (128,) fp32
  float* outp = (float*)d_out;               // (2048,16,128) fp32
  u16* ws = (u16*)d_ws;                      // keys + bf16 W + a_norm frag

  int pre_blocks = 1 + (QE_KEYS/8 + GW_ELEMS/8 + 255)/256;   // 42
  prepass_kernel<<<pre_blocks, 256, 0, stream>>>(qe, gw, adj, ws);
  core_snapshot_kernel<<<NB/2, 256, 0, stream>>>(la, ws, gb, outp);
}

// Round 2
// 88.532 us; speedup vs baseline: 1.0396x; 1.0216x over previous
//
#include <hip/hip_runtime.h>
#include <stdint.h>

typedef unsigned short u16;
typedef unsigned int u32;
typedef unsigned long long u64;

typedef __bf16 bf16x8 __attribute__((ext_vector_type(8)));
typedef float f32x4 __attribute__((ext_vector_type(4)));
typedef u16 u16x8 __attribute__((ext_vector_type(8)));

#define NQ 512
#define NC 16
#define NH 128
#define NB 2048
#define QE_KEYS (513*128)          // 65664 u16 keys
#define WT_OFF  QE_KEYS            // bf16 W copy
#define GW_ELEMS (128*128)
#define A_OFF (WT_OFF + GW_ELEMS)  // a_norm bf16, padded 16x32 (K 16->32 zeros)
#define LSEG 1088                  // per-item list segment (16*64=1024 + pad), u16
#define ESTC 544                   // u16 per core in sE: 4 quad-partials x (128+8 pad)
#define ESEG (16*ESTC)             // per-item sE segment, u16 (8704)

static __device__ __forceinline__ u16 f2bf_rne(float f){
  u32 u = __float_as_uint(f);
  u += 0x7fffu + ((u>>16)&1u);
  return (u16)(u>>16);
}
static __device__ __forceinline__ u32 pack_rne(float lo, float hi){
  return (u32)f2bf_rne(lo) | ((u32)f2bf_rne(hi)<<16);
}
// monotone key: unsigned compare on keys == float compare on bf16 values
static __device__ __forceinline__ u16 key_of(float f){
  u16 b = f2bf_rne(f);
  return (b & 0x8000u) ? (u16)~b : (u16)(b | 0x8000u);
}
// vectorized unkey of a u32 holding two keys:
// per half: set msb -> k^0x8000, clear msb -> ~k
static __device__ __forceinline__ u32 unkey2(u32 w){
  u32 s = w & 0x80008000u;
  return w ^ ~(s - (s >> 15));
}

union Frag { u32 u[4]; uint4 u4; bf16x8 f; };
union U8   { u16x8 v; int w[4]; u32 uw[4]; uint4 u4; u16 h[8]; };

// ---- prepass: keys, bf16 W, and precomputed a_norm A-fragment table ----
__global__ void prepass_kernel(const float* __restrict__ qe,
                               const float* __restrict__ gw,
                               const float* __restrict__ adj,
                               u16* __restrict__ ws)
{
  if (blockIdx.x == 0) {            // a_norm = adj * dinv_i * dinv_j, padded 16x32
    __shared__ float sD[16];
    int t = threadIdx.x;
    if (t < 16) {
      float s = 0.f;
      for (int i = 0; i < 16; ++i) s += adj[i*16 + t];
      sD[t] = (s > 0.f) ? (1.0f / sqrtf(s)) : 0.f;
    }
    __syncthreads();
    int i = t >> 4, jp = (t & 15) * 2;   // row i, cols jp, jp+1 of 32
    float lo = (jp   < 16) ? adj[i*16 + jp]   * sD[i] * sD[jp]   : 0.f;
    float hi = (jp+1 < 16) ? adj[i*16 + jp+1] * sD[i] * sD[jp+1] : 0.f;
    ((u32*)(ws + A_OFF))[t] = pack_rne(lo, hi);
    return;
  }
  int idx = (blockIdx.x - 1) * 256 + threadIdx.x;
  if (idx < QE_KEYS/8) {                       // key table
    int i8 = idx * 8;
    uint4 o;
    if (i8 >= 512*NH) {                        // row 512: key of +0.0
      o.x = 0x80008000u; o.y = 0x80008000u; o.z = 0x80008000u; o.w = 0x80008000u;
    } else {
      const float4* p = (const float4*)(qe + i8);
      float4 a = p[0], b = p[1];
      o.x = (u32)key_of(a.x) | ((u32)key_of(a.y)<<16);
      o.y = (u32)key_of(a.z) | ((u32)key_of(a.w)<<16);
      o.z = (u32)key_of(b.x) | ((u32)key_of(b.y)<<16);
      o.w = (u32)key_of(b.z) | ((u32)key_of(b.w)<<16);
    }
    *(uint4*)(ws + i8) = o;
  } else if (idx < QE_KEYS/8 + GW_ELEMS/8) {   // W -> bf16
    int j8 = (idx - QE_KEYS/8) * 8;
    const float4* p = (const float4*)(gw + j8);
    float4 a = p[0], b = p[1];
    uint4 o;
    o.x = pack_rne(a.x, a.y); o.y = pack_rne(a.z, a.w);
    o.z = pack_rne(b.x, b.y); o.w = pack_rne(b.z, b.w);
    *(uint4*)(ws + WT_OFF + j8) = o;
  }
}

// TEAM OF 2 WAVES per item: block = 256 threads = 2 items, grid = NB/2.
// Phase 2 processes cores in PAIRS (2x memory-level parallelism) and stores
// per-quad partial maxes (keys) to LDS instead of cross-lane reducing --
// removes 16 serialized ds_bpermute rounds per wave from the critical path.
__global__ __launch_bounds__(256, 4)
void core_snapshot_kernel(const int* __restrict__ la,
                          const u16* __restrict__ ws,
                          const float* __restrict__ gb,
                          float* __restrict__ outp)
{
  __shared__ __align__(16) u16 sListAll[2*LSEG];
  __shared__ __align__(16) u16 sEAll[2*ESEG];
  __shared__ int sCnt[2][2][16];    // [item][teamwave][core]

  const int tid  = threadIdx.x;
  const int lane = tid & 63;
  const int wv   = tid >> 6;
  const int it   = wv >> 1;         // item slot within block (0,1)
  const int tw   = wv & 1;          // team-wave index (0,1)
  const int m    = lane & 15;
  const int quad = lane >> 4;
  const int item = blockIdx.x*2 + it;
  u16* sList = sListAll + it*LSEG;
  u16* sE    = sEAll    + it*ESEG;
  const u16* qt = ws;
  const u16* wt = ws + WT_OFF;

  // prefill private list with 512 (pads gather the key-0 row == reference pad
  // semantics). Each wave fills half of the 1024 entries.
  {
    uint4 f = make_uint4(0x02000200u,0x02000200u,0x02000200u,0x02000200u);
    *(uint4*)&sList[tw*512 + lane*8] = f;
  }
  __syncthreads();   // B1: prefill complete before any entry writes

  // ---- phase 1: 4 chunks per wave; wave1 ranks offset by wave0 totals ----
  int av[4];
  #pragma unroll
  for (int ch = 0; ch < 4; ++ch) av[ch] = la[item*NQ + (tw*4 + ch)*64 + lane];
  const u64 lmask = (1ull << lane) - 1ull;
  u32 runbase = 0;     // lane c (<16) holds running count for core c (this wave)
  u32 rankrel[4];
  #pragma unroll
  for (int ch = 0; ch < 4; ++ch) {
    u32 cnt = 0, intra = 0;
    #pragma unroll
    for (int c = 0; c < 16; ++c) {
      u64 mk = __ballot(av[ch] == c);
      if (lane == c)    cnt   = (u32)__popcll(mk);
      if (av[ch] == c)  intra = (u32)__popcll(mk & lmask);
    }
    u32 base = (u32)__shfl((int)runbase, av[ch]);   // pre-chunk base, this wave
    rankrel[ch] = base + intra;
    runbase += cnt;
  }
  if (lane < 16) sCnt[it][tw][lane] = (int)runbase;
  if (tw == 0) {
    // wave0 ranks are final (base 0)
    #pragma unroll
    for (int ch = 0; ch < 4; ++ch) {
      u32 rank = rankrel[ch];
      // transposed: quad q's 16 entries [q*16+k] hold ranks q+4k
      if (rank < 64) sList[av[ch]*64 + (rank&3)*16 + (rank>>2)] = (u16)(ch*64 + lane);
    }
  }
  __syncthreads();   // B2: wave0 entries + both waves' counts visible
  u32 cntv;          // lane c: TOTAL count of core c (both waves)
  if (tw == 1) {
    #pragma unroll
    for (int ch = 0; ch < 4; ++ch) {
      u32 rank = (u32)sCnt[it][0][av[ch]] + rankrel[ch];
      if (rank < 64) sList[av[ch]*64 + (rank&3)*16 + (rank>>2)] = (u16)((4 + ch)*64 + lane);
    }
    cntv = runbase + (u32)((lane < 16) ? sCnt[it][0][lane] : 0);
  } else {
    cntv = runbase + (u32)((lane < 16) ? sCnt[it][1][lane] : 0);
  }
  __syncthreads();   // B3: all list entries visible

  // ---- phase 2: 8 cores per wave, processed in pairs; per-quad partials ----
  const u16* qb = qt + m*8;   // this lane's 8-dim chunk
  #pragma unroll 1
  for (int pp = 0; pp < 4; ++pp) {
    const int c0 = tw*8 + pp*2, c1 = c0 + 1;
    const int cnt0 = __shfl((int)cntv, c0);
    const int cnt1 = __shfl((int)cntv, c1);
    U8 S0a, S1a, S0b, S1b;
    S0a.u4 = *(const uint4*)&sList[c0*64 + quad*16];      // ranks quad+4k, k=0..7
    S1a.u4 = *(const uint4*)&sList[c0*64 + quad*16 + 8];  // k=8..15
    S0b.u4 = *(const uint4*)&sList[c1*64 + quad*16];
    S1b.u4 = *(const uint4*)&sList[c1*64 + quad*16 + 8];
    U8 Ta[8], Tb[8];
    #pragma unroll
    for (int k = 0; k < 8; ++k) Ta[k].u4 = *(const uint4*)(qb + (int)S0a.h[k]*NH);
    #pragma unroll
    for (int k = 0; k < 8; ++k) Tb[k].u4 = *(const uint4*)(qb + (int)S0b.h[k]*NH);

    U8 A; A.v = (u16x8)0;                                 // key 0 < all value keys
    #pragma unroll
    for (int k = 0; k < 8; ++k) A.v = __builtin_elementwise_max(A.v, Ta[k].v);
    if (cnt0 > 32) {   // wave-uniform; ranks 32..47 (pads give key(+0))
      U8 T[4];
      #pragma unroll
      for (int k = 0; k < 4; ++k) T[k].u4 = *(const uint4*)(qb + (int)S1a.h[k]*NH);
      #pragma unroll
      for (int k = 0; k < 4; ++k) A.v = __builtin_elementwise_max(A.v, T[k].v);
    }
    if (cnt0 > 48) {   // ranks 48..63
      U8 T[4];
      #pragma unroll
      for (int k = 0; k < 4; ++k) T[k].u4 = *(const uint4*)(qb + (int)S1a.h[4+k]*NH);
      #pragma unroll
      for (int k = 0; k < 4; ++k) A.v = __builtin_elementwise_max(A.v, T[k].v);
    }
    // relu via key(+0): REQUIRED when cnt<64 even if no pad fetched (e.g. cnt==32)
    if (cnt0 < 64) { U8 Z; Z.v = (u16x8)(u16)0x8000u; A.v = __builtin_elementwise_max(A.v, Z.v); }
    *(uint4*)&sE[c0*ESTC + quad*136 + m*8] = A.u4;        // per-quad partial keys

    U8 B; B.v = (u16x8)0;
    #pragma unroll
    for (int k = 0; k < 8; ++k) B.v = __builtin_elementwise_max(B.v, Tb[k].v);
    if (cnt1 > 32) {
      U8 T[4];
      #pragma unroll
      for (int k = 0; k < 4; ++k) T[k].u4 = *(const uint4*)(qb + (int)S1b.h[k]*NH);
      #pragma unroll
      for (int k = 0; k < 4; ++k) B.v = __builtin_elementwise_max(B.v, T[k].v);
    }
    if (cnt1 > 48) {
      U8 T[4];
      #pragma unroll
      for (int k = 0; k < 4; ++k) T[k].u4 = *(const uint4*)(qb + (int)S1b.h[4+k]*NH);
      #pragma unroll
      for (int k = 0; k < 4; ++k) B.v = __builtin_elementwise_max(B.v, T[k].v);
    }
    if (cnt1 < 64) { U8 Z; Z.v = (u16x8)(u16)0x8000u; B.v = __builtin_elementwise_max(B.v, Z.v); }
    *(uint4*)&sE[c1*ESTC + quad*136 + m*8] = B.u4;
  }
  __syncthreads();   // B4: all partials visible to both waves

  // ---- phases 3+4 fused per o-tile (4 tiles per wave) ----
  // af[ks]: combine 4 quad-partials of core m with packed-u16 max, then unkey.
  bf16x8 af[4];
  #pragma unroll
  for (int ks = 0; ks < 4; ++ks) {
    const u16* pb = &sE[m*ESTC + ks*32 + quad*8];
    U8 P0, P1, P2, P3;
    P0.u4 = *(const uint4*)(pb);
    P1.u4 = *(const uint4*)(pb + 136);
    P2.u4 = *(const uint4*)(pb + 272);
    P3.u4 = *(const uint4*)(pb + 408);
    P0.v = __builtin_elementwise_max(P0.v, P1.v);
    P2.v = __builtin_elementwise_max(P2.v, P3.v);
    P0.v = __builtin_elementwise_max(P0.v, P2.v);
    Frag f;
    #pragma unroll
    for (int j = 0; j < 4; ++j) f.u[j] = unkey2(P0.uw[j]);
    af[ks] = f.f;
  }
  Frag anf;       // a_norm A-fragment (precomputed, padded K zeros)
  anf.u4 = *(const uint4*)(ws + A_OFF + m*32 + quad*8);

  #pragma unroll
  for (int tt = 0; tt < 4; ++tt) {
    int t = tw*4 + tt;
    // H tile: C-layout acc[r] = H[core=quad*4+r][o=t*16+m]
    f32x4 acc = {0.f, 0.f, 0.f, 0.f};
    #pragma unroll
    for (int ks = 0; ks < 4; ++ks) {
      bf16x8 bfr = *(const bf16x8*)(wt + (t*16 + m)*NH + ks*32 + quad*8);
      acc = __builtin_amdgcn_mfma_f32_16x16x32_bf16(af[ks], bfr, acc, 0, 0, 0);
    }
    // B-frag for out-GEMM: lane(m,q) j-th elem = H[core=q*8+j][o=t*16+m], q<2
    float d16[4], d32[4], lo[4], hi[4];
    #pragma unroll
    for (int r = 0; r < 4; ++r) {
      d16[r] = __shfl_down(acc[r], 16);
      d32[r] = __shfl_down(acc[r], 32);
    }
    #pragma unroll
    for (int r = 0; r < 4; ++r) {
      lo[r] = (quad == 0) ? acc[r] : d16[r];
      hi[r] = (quad == 0) ? d16[r] : d32[r];
    }
    Frag hb;
    hb.u[0] = pack_rne(lo[0], lo[1]); hb.u[1] = pack_rne(lo[2], lo[3]);
    hb.u[2] = pack_rne(hi[0], hi[1]); hb.u[3] = pack_rne(hi[2], hi[3]);
    if (quad >= 2) { hb.u[0]=0; hb.u[1]=0; hb.u[2]=0; hb.u[3]=0; }  // K-pad
    float biasv = gb[t*16 + m];
    f32x4 o4 = {biasv, biasv, biasv, biasv};
    o4 = __builtin_amdgcn_mfma_f32_16x16x32_bf16(anf.f, hb.f, o4, 0, 0, 0);
    // C/D: col=lane&15 (o in tile), row=quad*4+reg (core)
    float* op = outp + item*(NC*NH) + t*16 + m;
    #pragma unroll
    for (int r = 0; r < 4; ++r) op[(quad*4 + r)*NH] = o4[r];
  }
}

extern "C" void kernel_launch(void* const* d_in, const int* in_sizes, int n_in,
                              void* d_out, int out_size, void* d_ws, size_t ws_size,
                              hipStream_t stream) {
  const int*   la  = (const int*)d_in[0];    // (2048, 512) int32
  const float* adj = (const float*)d_in[1];  // (16,16) fp32
  const float* qe  = (const float*)d_in[2];  // (513,128) fp32
  const float* gw  = (const float*)d_in[3];  // (128,128) fp32
  const float* gb  = (const float*)d_in[4];  // (128,) fp32
  float* outp = (float*)d_out;               // (2048,16,128) fp32
  u16* ws = (u16*)d_ws;                      // keys + bf16 W + a_norm frag

  int pre_blocks = 1 + (QE_KEYS/8 + GW_ELEMS/8 + 255)/256;   // 42
  prepass_kernel<<<pre_blocks, 256, 0, stream>>>(qe, gw, adj, ws);
  core_snapshot_kernel<<<NB/2, 256, 0, stream>>>(la, ws, gb, outp);
}